// Round 10
// baseline (224.600 us; speedup 1.0000x reference)
//
#include <hip/hip_runtime.h>
#include <hip/hip_bf16.h>

// B=32, L=576, DIM=192, D_INNER=384, D_STATE=16, DT_RANK=12, D_CONV=4
#define NC 32
#define CL 18

typedef __attribute__((ext_vector_type(8))) short short8;
typedef __attribute__((ext_vector_type(4))) float f32x4;
typedef __attribute__((ext_vector_type(2))) float f32x2;

__device__ __forceinline__ float sigm(float x){ return 1.0f/(1.0f+__expf(-x)); }

__device__ __forceinline__ ushort f2bf(float f){
  unsigned u = __float_as_uint(f);
  unsigned r = (u + 0x7fffu + ((u>>16)&1u)) >> 16;
  return (ushort)r;
}
__device__ __forceinline__ float bf2f(ushort h){ return __uint_as_float(((unsigned)h)<<16); }

// log-depth power ladder: dA2[p] = {e1^(2p+1), e1^(2p+2)}  (verified safe in R3)
__device__ __forceinline__ void build_dA2_fast(float e1, f32x2 dA2[8]){
  float e2 = e1*e1;
  f32x2 d0 = {e1, e2};
  float e4 = e2*e2;
  f32x2 e2v = {e2,e2}, e4v = {e4,e4};
  f32x2 d1 = d0*e2v;
  f32x2 d2 = d0*e4v;
  f32x2 d3 = d1*e4v;
  float e8 = e4*e4;
  f32x2 e8v = {e8,e8};
  dA2[0]=d0; dA2[1]=d1; dA2[2]=d2; dA2[3]=d3;
  dA2[4]=d0*e8v; dA2[5]=d1*e8v; dA2[6]=d2*e8v; dA2[7]=d3*e8v;
}

// ---------------- fused preprocessing ----------------
__global__ __launch_bounds__(256) void k_prep_all(
    const float* __restrict__ patch_w, const float* __restrict__ f_in_w,
    const float* __restrict__ b_in_w,
    const float* __restrict__ f_xw, const float* __restrict__ b_xw,
    const float* __restrict__ f_cw, const float* __restrict__ b_cw,
    const float* __restrict__ f_al, const float* __restrict__ b_al,
    const float* __restrict__ fc_w, const float* __restrict__ f_ow,
    const float* __restrict__ b_ow,
    ushort* __restrict__ pw_h, ushort* __restrict__ pw_l,
    ushort* __restrict__ iw_h, ushort* __restrict__ iw_l,
    ushort* __restrict__ xw_h, ushort* __restrict__ xw_l,
    float* __restrict__ cwT, float* __restrict__ Abuf,
    float* __restrict__ A0fl, float* __restrict__ W2){
  const int bx = blockIdx.x, t = threadIdx.x;
  if (bx < 1728){
    int which = bx/576;
    int i = (bx - which*576)*256 + t;          // < 147456
    if (which==0){
      float f = patch_w[i];
      ushort hb = f2bf(f);
      pw_h[i]=hb; pw_l[i]=f2bf(f - bf2f(hb));
    } else {
      const float* src = (which==1) ? f_in_w : b_in_w;
      int dirofs = (which==1) ? 0 : 48;
      float f = src[i];
      int n = i/192, k = i%192;
      int nblk = n>>4, r = n&15, kblk = k>>5, kk = k&31;
      int lane = r + ((kk>>3)<<4), j = kk&7;
      size_t idx = ((size_t)((nblk+dirofs)*6 + kblk)*64 + lane)*8 + j;
      ushort hb = f2bf(f);
      iw_h[idx]=hb; iw_l[idx]=f2bf(f - bf2f(hb));
    }
  } else if (bx < 1872){
    int i = (bx-1728)*256 + t;                 // < 36864
    int dir=i/(48*384), rem=i%(48*384), n=rem/384, k=rem%384;
    float v = (n<44) ? (dir?b_xw:f_xw)[n*384+k] : 0.f;
    ushort hb = f2bf(v);
    xw_h[i]=hb; xw_l[i]=f2bf(v - bf2f(hb));
  } else if (bx < 1884){
    int i = (bx-1872)*256 + t;                 // < 3072
    int dir=i/1536, rem=i%1536, j=rem/384, k=rem%384;
    cwT[i] = (dir ? b_cw : f_cw)[k*4+j];
  } else if (bx < 1887){
    int i = (bx-1884)*256 + t;
    if (i < 768){
      int dir=i/384, di=i%384;
      const float* alp = (dir?b_al:f_al) + di*16;
      float A0 = -expf(alp[0]);
      bool fast = true;
      Abuf[(size_t)i*16] = A0;
      #pragma unroll
      for (int s=1;s<16;s++){
        float A = -expf(alp[s]);
        Abuf[(size_t)i*16+s] = A;
        fast = fast && (fabsf(A - (s+1)*A0) <= 1e-5f*(s+1)*fabsf(A0));
      }
      A0fl[i*2]=A0; A0fl[i*2+1]=fast?1.f:0.f;
    }
  } else {
    int i = (bx-1887)*256 + t;
    if (i < 768){
      int dir=i/384, di=i%384;
      const float* ow = dir ? b_ow : f_ow;
      float a0=0.f,a1=0.f,a2=0.f,a3=0.f;
      for (int d=0; d<192; ++d){
        float o = ow[d*384 + di];
        a0 += fc_w[0*192+d]*o; a1 += fc_w[1*192+d]*o;
        a2 += fc_w[2*192+d]*o; a3 += fc_w[3*192+d]*o;
      }
      W2[(0*2+dir)*384+di]=a0; W2[(1*2+dir)*384+di]=a1;
      W2[(2*2+dir)*384+di]=a2; W2[(3*2+dir)*384+di]=a3;
    }
  }
}

// ---------------- K1: patch embed MFMA GEMM + fused LN -> fragment-packed tokf ----------------
// BM=64, block=1024, 16 waves. Addresses hoisted out of the K-loop (no data prefetch).
__global__ __launch_bounds__(1024) void k_patch(
    const float* __restrict__ x,
    const ushort* __restrict__ pw_h, const ushort* __restrict__ pw_l,
    const float* __restrict__ pb, const float* __restrict__ lng,
    const float* __restrict__ lnb,
    ushort* __restrict__ tokf_h, ushort* __restrict__ tokf_l,
    int b0, int Mc){
  __shared__ __align__(16) char sBmem[49152];   // sBh 24KB + sBl 24KB ; aliased as sT
  __shared__ __align__(16) ushort sAh[64*64], sAl[64*64];  // 8KB + 8KB
  __shared__ float sLN[4][64][2];               // 2KB
  ushort* sBh = (ushort*)sBmem;
  ushort* sBl = (ushort*)(sBmem + 24576);
  const int tid = threadIdx.x;
  const int m0 = blockIdx.x*64;
  const int lane = tid&63, w = tid>>6;          // w 0..15
  const int wr = w>>2, wc = w&3;
  const int r = lane&15, g = lane>>4;
  f32x4 acc[3];
  #pragma unroll
  for (int i=0;i<3;i++) acc[i] = (f32x4){0.f,0.f,0.f,0.f};

  // hoisted per-thread staging geometry
  const int mA = tid>>4, remA = tid&15, ppA = remA>>2, qqA = remA&3;
  const int rmA = m0 + mA;
  const bool okA = (rmA < Mc);
  size_t baseA = 0;
  if (okA){
    int b = b0 + rmA/576, l = rmA%576, hp = l/24, wp = l%24;
    baseA = ((size_t)(b*3)*384 + hp*16 + ppA)*96 + wp*4 + qqA;
  }
  const int byteA = (mA*128 + ppA*32 + qqA*8) ^ ((mA&7)<<4);
  const int nB0 = tid>>3, k8B0 = tid&7;
  const size_t baseB0 = (size_t)nB0*768 + k8B0*8;
  const int byteB0 = (nB0*128 + k8B0*16) ^ ((nB0&7)<<4);
  const bool okB1 = (tid < 512);
  const int fB1 = tid + 1024;
  const int nB1 = fB1>>3, k8B1 = fB1&7;
  const size_t baseB1 = (size_t)nB1*768 + k8B1*8;
  const int byteB1 = (nB1*128 + k8B1*16) ^ ((nB1&7)<<4);

  for (int s=0;s<12;s++){
    {
      float4 v = make_float4(0.f,0.f,0.f,0.f);
      if (okA){
        size_t so = (size_t)((s>>2)*384 + (s&3)*4)*96;   // wave-uniform SALU
        v = reinterpret_cast<const float4*>(x)[baseA + so];
      }
      ushort4 hv, lv;
      hv.x=f2bf(v.x); lv.x=f2bf(v.x-bf2f(hv.x));
      hv.y=f2bf(v.y); lv.y=f2bf(v.y-bf2f(hv.y));
      hv.z=f2bf(v.z); lv.z=f2bf(v.z-bf2f(hv.z));
      hv.w=f2bf(v.w); lv.w=f2bf(v.w-bf2f(hv.w));
      *reinterpret_cast<ushort4*>((char*)sAh + byteA) = hv;
      *reinterpret_cast<ushort4*>((char*)sAl + byteA) = lv;
    }
    {
      uint4 bh = *reinterpret_cast<const uint4*>(pw_h + baseB0 + s*64);
      uint4 bl = *reinterpret_cast<const uint4*>(pw_l + baseB0 + s*64);
      *reinterpret_cast<uint4*>((char*)sBh + byteB0) = bh;
      *reinterpret_cast<uint4*>((char*)sBl + byteB0) = bl;
      if (okB1){
        uint4 bh1 = *reinterpret_cast<const uint4*>(pw_h + baseB1 + s*64);
        uint4 bl1 = *reinterpret_cast<const uint4*>(pw_l + baseB1 + s*64);
        *reinterpret_cast<uint4*>((char*)sBh + byteB1) = bh1;
        *reinterpret_cast<uint4*>((char*)sBl + byteB1) = bl1;
      }
    }
    __syncthreads();
    #pragma unroll
    for (int kk=0;kk<2;kk++){
      int arow = wr*16 + r;
      int abyte = (arow*128 + kk*64 + g*16) ^ ((arow&7)<<4);
      short8 ah = *reinterpret_cast<const short8*>((char*)sAh + abyte);
      short8 al = *reinterpret_cast<const short8*>((char*)sAl + abyte);
      #pragma unroll
      for (int nfl=0; nfl<3; nfl++){
        int brow = (wc*3+nfl)*16 + r;
        int bbyte = (brow*128 + kk*64 + g*16) ^ ((brow&7)<<4);
        short8 bh = *reinterpret_cast<const short8*>((char*)sBh + bbyte);
        short8 bll = *reinterpret_cast<const short8*>((char*)sBl + bbyte);
        acc[nfl] = __builtin_amdgcn_mfma_f32_16x16x32_bf16(ah, bh, acc[nfl], 0,0,0);
        acc[nfl] = __builtin_amdgcn_mfma_f32_16x16x32_bf16(ah, bll, acc[nfl], 0,0,0);
        acc[nfl] = __builtin_amdgcn_mfma_f32_16x16x32_bf16(al, bh, acc[nfl], 0,0,0);
      }
    }
    __syncthreads();
  }
  float pbv[3], gv[3], bv[3];
  #pragma unroll
  for (int nfl=0;nfl<3;nfl++){
    int col = (wc*3+nfl)*16 + r;
    pbv[nfl]=pb[col]; gv[nfl]=lng[col]; bv[nfl]=lnb[col];
  }
  #pragma unroll
  for (int nfl=0;nfl<3;nfl++)
    #pragma unroll
    for (int q=0;q<4;q++) acc[nfl][q] += pbv[nfl];
  float sum[4]={0,0,0,0}, sq[4]={0,0,0,0};
  #pragma unroll
  for (int nfl=0;nfl<3;nfl++)
    #pragma unroll
    for (int q=0;q<4;q++){ float v=acc[nfl][q]; sum[q]+=v; sq[q]+=v*v; }
  #pragma unroll
  for (int off=1; off<16; off<<=1){
    #pragma unroll
    for (int q=0;q<4;q++){
      sum[q]+=__shfl_xor(sum[q],off);
      sq[q] +=__shfl_xor(sq[q],off);
    }
  }
  if (r==0){
    #pragma unroll
    for (int q=0;q<4;q++){
      int row = wr*16 + g*4 + q;
      sLN[wc][row][0]=sum[q]; sLN[wc][row][1]=sq[q];
    }
  }
  __syncthreads();
  float* sT = (float*)sBmem;                    // 64 x 192 f32 (48KB)
  #pragma unroll
  for (int q=0;q<4;q++){
    int rl = wr*16 + g*4 + q;
    float stot = sLN[0][rl][0]+sLN[1][rl][0]+sLN[2][rl][0]+sLN[3][rl][0];
    float qtot = sLN[0][rl][1]+sLN[1][rl][1]+sLN[2][rl][1]+sLN[3][rl][1];
    float mu = stot*(1.f/192.f);
    float var = qtot*(1.f/192.f) - mu*mu;
    float rs = rsqrtf(var + 1e-5f);
    #pragma unroll
    for (int nfl=0;nfl<3;nfl++)
      sT[rl*192 + (wc*3+nfl)*16 + r] = (acc[nfl][q]-mu)*rs*gv[nfl] + bv[nfl];
  }
  __syncthreads();
  const int mB = m0>>4;
  #pragma unroll
  for (int i=0;i<2;i++){
    int fl = tid + 1024*i;                      // < 1536
    if (fl < 1536){
      int mb = fl/384, rem = fl-mb*384, kb = rem>>6, ln = rem&63;
      int rr = ln&15, gq = ln>>4;
      const float* sp = sT + (mb*16+rr)*192 + kb*32 + gq*8;
      short8 hv, lv;
      #pragma unroll
      for (int j=0;j<8;j++){
        float v = sp[j];
        ushort hb = f2bf(v);
        hv[j] = (short)hb;
        lv[j] = (short)f2bf(v - bf2f(hb));
      }
      size_t o = ((size_t)((mB+mb)*6 + kb)*64 + ln)*8;
      *reinterpret_cast<short8*>(tokf_h + o) = hv;
      *reinterpret_cast<short8*>(tokf_l + o) = lv;
    }
  }
}

// ---------------- K2: in_proj MFMA GEMM — LDS-staged 128x128 tiles, vectorized epilogue ----------------
__global__ __launch_bounds__(1024) void k_inproj(
    const ushort* __restrict__ tokf_h, const ushort* __restrict__ tokf_l,
    const ushort* __restrict__ iw_h, const ushort* __restrict__ iw_l,
    float* __restrict__ xib, ushort* __restrict__ zb, int Bc, int Mc){
  __shared__ __align__(16) char sMem[65536];
  ushort* sAh = (ushort*)sMem;                 // 16 frags * 512 ushorts = 16KB
  ushort* sAl = (ushort*)(sMem + 16384);
  ushort* sBh = (ushort*)(sMem + 32768);
  ushort* sBl = (ushort*)(sMem + 49152);
  const int tid = threadIdx.x;
  const int lane = tid&63, w = tid>>6;         // 16 waves
  const int wr = w>>2, wc = w&3;
  const int r = lane&15, g = lane>>4;
  const int m0 = blockIdx.x*128;
  const int mb0 = blockIdx.x*8;
  const int nb0 = blockIdx.y*8;                // iw frag row (dir already encoded: 0..95)
  const int n0d = (blockIdx.y%6)*128;          // col within this dir (0..767)
  const bool dir1 = (blockIdx.y >= 6);
  const bool isZ = ((blockIdx.y%6) >= 3);

  f32x4 acc[2][2];
  #pragma unroll
  for (int a=0;a<2;a++)
    #pragma unroll
    for (int b=0;b<2;b++) acc[a][b] = (f32x4){0.f,0.f,0.f,0.f};

  for (int s=0;s<3;s++){
    {
      const int f = w;
      const int mf = f>>1, kk = f&1;
      const size_t ga = ((size_t)((mb0+mf)*6 + 2*s+kk)*64 + lane)*8;
      const size_t gb = ((size_t)((nb0+mf)*6 + 2*s+kk)*64 + lane)*8;
      const int so = f*512 + lane*8;
      *reinterpret_cast<short8*>(sAh+so) = *reinterpret_cast<const short8*>(tokf_h+ga);
      *reinterpret_cast<short8*>(sBh+so) = *reinterpret_cast<const short8*>(iw_h+gb);
      if (!isZ){
        *reinterpret_cast<short8*>(sAl+so) = *reinterpret_cast<const short8*>(tokf_l+ga);
        *reinterpret_cast<short8*>(sBl+so) = *reinterpret_cast<const short8*>(iw_l+gb);
      }
    }
    __syncthreads();
    #pragma unroll
    for (int kk=0;kk<2;kk++){
      short8 ah[2], al[2];
      #pragma unroll
      for (int mf=0;mf<2;mf++){
        const int fo = ((wr*2+mf)*2+kk)*512 + lane*8;
        ah[mf] = *reinterpret_cast<const short8*>(sAh+fo);
        if (!isZ) al[mf] = *reinterpret_cast<const short8*>(sAl+fo);
      }
      #pragma unroll
      for (int nf=0;nf<2;nf++){
        const int fo = ((wc*2+nf)*2+kk)*512 + lane*8;
        short8 bh = *reinterpret_cast<const short8*>(sBh+fo);
        if (isZ){
          #pragma unroll
          for (int mf=0;mf<2;mf++)
            acc[mf][nf] = __builtin_amdgcn_mfma_f32_16x16x32_bf16(ah[mf], bh, acc[mf][nf], 0,0,0);
        } else {
          short8 bl = *reinterpret_cast<const short8*>(sBl+fo);
          #pragma unroll
          for (int mf=0;mf<2;mf++){
            acc[mf][nf] = __builtin_amdgcn_mfma_f32_16x16x32_bf16(ah[mf], bh, acc[mf][nf], 0,0,0);
            acc[mf][nf] = __builtin_amdgcn_mfma_f32_16x16x32_bf16(ah[mf], bl, acc[mf][nf], 0,0,0);
            acc[mf][nf] = __builtin_amdgcn_mfma_f32_16x16x32_bf16(al[mf], bh, acc[mf][nf], 0,0,0);
          }
        }
      }
    }
    __syncthreads();
  }

  float* sT = reinterpret_cast<float*>(sMem);  // 64 x 132 f32 = 33.8KB
  const int h_of_w = wr>>1;
  #pragma unroll
  for (int h=0; h<2; h++){
    if (h==1) __syncthreads();
    if (h_of_w == h){
      #pragma unroll
      for (int mf=0;mf<2;mf++)
        #pragma unroll
        for (int nf=0;nf<2;nf++)
          #pragma unroll
          for (int q=0;q<4;q++){
            int rl = (wr&1)*32 + mf*16 + g*4 + q;
            int c  = wc*32 + nf*16 + r;
            sT[rl*132 + c] = acc[mf][nf][q];
          }
    }
    __syncthreads();
    {
      const int rl = tid>>4, cg = tid&15;
      const int rm = m0 + h*64 + rl;
      if (rm < Mc){
        size_t row;
        if (dir1){
          int bl = rm/576, l = rm - bl*576;
          row = (size_t)(Bc + bl)*576 + (575-l);
        } else {
          row = (size_t)rm;
        }
        const float* sp = sT + rl*132 + cg*8;
        if (!isZ){
          *reinterpret_cast<f32x4*>(xib + row*384 + n0d + cg*8)     = *reinterpret_cast<const f32x4*>(sp);
          *reinterpret_cast<f32x4*>(xib + row*384 + n0d + cg*8 + 4) = *reinterpret_cast<const f32x4*>(sp+4);
        } else {
          short8 hv;
          #pragma unroll
          for (int j=0;j<8;j++){
            float v = sp[j];
            v = v*sigm(v);
            hv[j] = (short)f2bf(v);
          }
          *reinterpret_cast<short8*>(zb + row*384 + (n0d-384) + cg*8) = hv;
        }
      }
    }
  }
}

// ---------------- K3: fused conv1d+silu+x_proj as MFMA GEMM (N=48), writes xc bf16 ----------------
__global__ __launch_bounds__(256) void k_convx(
    const float* __restrict__ xib, const float* __restrict__ cwT,
    const float* __restrict__ f_cb, const float* __restrict__ b_cb,
    const ushort* __restrict__ xw_h, const ushort* __restrict__ xw_l,
    float* __restrict__ proj, ushort* __restrict__ xcb, int Bc){
  __shared__ __align__(16) float sRaw[67*64];
  __shared__ __align__(16) ushort sAh[64*64], sAl[64*64];
  __shared__ __align__(16) ushort sBh[48*64], sBl[48*64];
  const int dir = blockIdx.z, blk = blockIdx.y, l0 = blockIdx.x*64;
  const int tid = threadIdx.x, lane = tid&63, w = tid>>6;
  const int r = lane&15, g = lane>>4;
  const size_t seq = ((size_t)dir*Bc + blk)*576;
  const float* cwTd = cwT + dir*1536;
  const float* cbp  = dir?b_cb:f_cb;
  const ushort* bhp = xw_h + dir*48*384;
  const ushort* blp = xw_l + dir*48*384;
  f32x4 acc[3];
  #pragma unroll
  for (int i=0;i<3;i++) acc[i] = (f32x4){0.f,0.f,0.f,0.f};

  for (int kc=0; kc<6; ++kc){
    #pragma unroll
    for (int i=0;i<5;i++){
      int f = tid + i*256;
      if (f < 67*16){
        int rr = f>>4, kq = f&15;
        int l = l0 + rr - 3;
        float4 v = make_float4(0.f,0.f,0.f,0.f);
        if (l >= 0) v = *reinterpret_cast<const float4*>(xib + (seq+l)*384 + kc*64 + kq*4);
        int kqs = kq ^ (rr&15);
        *reinterpret_cast<float4*>(sRaw + rr*64 + kqs*4) = v;
      }
    }
    __syncthreads();
    #pragma unroll
    for (int i=0;i<4;i++){
      int f = tid + i*256;                 // < 1024
      int m = f>>4, kq = f&15;
      float4 a = reinterpret_cast<const float4*>(cbp)[kc*16 + kq];
      #pragma unroll
      for (int j=0;j<4;j++){
        int rr = m + j;
        float4 rv = *reinterpret_cast<const float4*>(sRaw + rr*64 + (kq ^ (rr&15))*4);
        float4 cv = reinterpret_cast<const float4*>(cwTd)[j*96 + kc*16 + kq];
        a.x += cv.x*rv.x; a.y += cv.y*rv.y; a.z += cv.z*rv.z; a.w += cv.w*rv.w;
      }
      a.x = a.x*sigm(a.x); a.y = a.y*sigm(a.y); a.z = a.z*sigm(a.z); a.w = a.w*sigm(a.w);
      ushort4 hv, lv;
      hv.x=f2bf(a.x); lv.x=f2bf(a.x-bf2f(hv.x));
      hv.y=f2bf(a.y); lv.y=f2bf(a.y-bf2f(hv.y));
      hv.z=f2bf(a.z); lv.z=f2bf(a.z-bf2f(hv.z));
      hv.w=f2bf(a.w); lv.w=f2bf(a.w-bf2f(hv.w));
      *reinterpret_cast<ushort4*>(xcb + (seq + l0 + m)*384 + kc*64 + kq*4) = hv;
      int byte = (m*128 + kq*8) ^ ((m&7)<<4);
      *reinterpret_cast<ushort4*>((char*)sAh + byte) = hv;
      *reinterpret_cast<ushort4*>((char*)sAl + byte) = lv;
    }
    #pragma unroll
    for (int i=0;i<2;i++){
      int f = tid + i*256;
      if (f < 384){
        int n = f>>3, k8 = f&7;
        size_t gi = (size_t)n*384 + kc*64 + k8*8;
        uint4 vh = *reinterpret_cast<const uint4*>(bhp + gi);
        uint4 vl = *reinterpret_cast<const uint4*>(blp + gi);
        int byte = (n*128 + k8*16) ^ ((n&7)<<4);
        *reinterpret_cast<uint4*>((char*)sBh + byte) = vh;
        *reinterpret_cast<uint4*>((char*)sBl + byte) = vl;
      }
    }
    __syncthreads();
    #pragma unroll
    for (int kk=0;kk<2;kk++){
      int arow = w*16 + r;
      int abyte = (arow*128 + kk*64 + g*16) ^ ((arow&7)<<4);
      short8 ah = *reinterpret_cast<const short8*>((char*)sAh + abyte);
      short8 al = *reinterpret_cast<const short8*>((char*)sAl + abyte);
      #pragma unroll
      for (int nf=0;nf<3;nf++){
        int brow = nf*16 + r;
        int bbyte = (brow*128 + kk*64 + g*16) ^ ((brow&7)<<4);
        short8 bh = *reinterpret_cast<const short8*>((char*)sBh + bbyte);
        short8 bll = *reinterpret_cast<const short8*>((char*)sBl + bbyte);
        acc[nf] = __builtin_amdgcn_mfma_f32_16x16x32_bf16(ah, bh, acc[nf], 0,0,0);
        acc[nf] = __builtin_amdgcn_mfma_f32_16x16x32_bf16(ah, bll, acc[nf], 0,0,0);
        acc[nf] = __builtin_amdgcn_mfma_f32_16x16x32_bf16(al, bh, acc[nf], 0,0,0);
      }
    }
    __syncthreads();
  }
  #pragma unroll
  for (int nf=0;nf<3;nf++){
    int col = nf*16 + r;
    if (col < 44){
      #pragma unroll
      for (int q=0;q<4;q++){
        int l = l0 + w*16 + g*4 + q;
        proj[(seq+l)*44 + col] = acc[nf][q];
      }
    }
  }
}

// ---------------- K4a: chunked scan phase 1 (h0=0), 2 channels/thread; saves dt for p2 ----------------
__global__ __launch_bounds__(256) void k_scan_p1(
    const ushort* __restrict__ zb, const ushort* __restrict__ xcb,
    const float* __restrict__ proj,
    const float* __restrict__ f_dtw, const float* __restrict__ b_dtw,
    const float* __restrict__ f_dtb, const float* __restrict__ b_dtb,
    const float* __restrict__ A0fl, const float* __restrict__ Abuf,
    const float* __restrict__ f_D,  const float* __restrict__ b_D,
    const float* __restrict__ W2, float* __restrict__ dtend,
    float* __restrict__ hbuf, float* __restrict__ dtsav,
    float* __restrict__ part, int b0, int Bc){
  const int dir=blockIdx.z, bl=blockIdx.y;
  const int gg=blockIdx.x>>3, cq=blockIdx.x&7;          // gg 0..2
  const int wv=threadIdx.x>>6, lane=threadIdx.x&63;
  const int c = cq*4 + wv;
  const int di0 = gg*128 + lane*2;
  const size_t seq = ((size_t)dir*Bc + bl)*576;
  const float* dtwp = (dir?b_dtw:f_dtw) + (size_t)di0*12;
  f32x2 dtw2[12];
  {
    const float4* dp = reinterpret_cast<const float4*>(dtwp);
    #pragma unroll
    for (int i=0;i<3;i++){
      float4 fa = dp[i], fb = dp[i+3];
      dtw2[4*i+0] = (f32x2){fa.x, fb.x};
      dtw2[4*i+1] = (f32x2){fa.y, fb.y};
      dtw2[4*i+2] = (f32x2){fa.z, fb.z};
      dtw2[4*i+3] = (f32x2){fa.w, fb.w};
    }
  }
  float2 dtb2 = *reinterpret_cast<const float2*>((dir?b_dtb:f_dtb)+di0);
  float4 af = *reinterpret_cast<const float4*>(A0fl + ((size_t)dir*384+di0)*2);
  const float A0a = af.x, A0b = af.z;
  const bool fast = (af.y != 0.f) && (af.w != 0.f);
  const float* Abp = Abuf + ((size_t)dir*384+di0)*16;   // rows a (0..15), b (16..31)
  float2 Dv2 = *reinterpret_cast<const float2*>((dir?b_D:f_D)+di0);
  float2 w2c2[4];
  #pragma unroll
  for (int ch=0;ch<4;ch++)
    w2c2[ch] = *reinterpret_cast<const float2*>(W2 + (ch*2+dir)*384 + di0);
  f32x2 h2a[8], h2b[8];
  #pragma unroll
  for (int p=0;p<8;p++){ h2a[p]=(f32x2){0.f,0.f}; h2b[p]=(f32x2){0.f,0.f}; }
  float Sa=0.f, Sb=0.f, cuma=0.f, cumb=0.f;
  const int l0 = c*CL;
  const int pbase = (int)((seq + (size_t)l0)*44);
  const ushort* xcp = xcb + di0;
  const ushort* zbp2 = zb + di0;
  for (int j=0;j<CL;j++){
    const size_t row = seq + l0 + j;
    const int po = __builtin_amdgcn_readfirstlane(pbase + j*44);
    const float4* pr4 = reinterpret_cast<const float4*>(proj + po);
    float4 t0=pr4[0], t1=pr4[1], t2=pr4[2];
    f32x2 dtin2 = (f32x2){dtb2.x, dtb2.y};
    dtin2 += (f32x2){t0.x,t0.x}*dtw2[0]; dtin2 += (f32x2){t0.y,t0.y}*dtw2[1];
    dtin2 += (f32x2){t0.z,t0.z}*dtw2[2]; dtin2 += (f32x2){t0.w,t0.w}*dtw2[3];
    dtin2 += (f32x2){t1.x,t1.x}*dtw2[4]; dtin2 += (f32x2){t1.y,t1.y}*dtw2[5];
    dtin2 += (f32x2){t1.z,t1.z}*dtw2[6]; dtin2 += (f32x2){t1.w,t1.w}*dtw2[7];
    dtin2 += (f32x2){t2.x,t2.x}*dtw2[8]; dtin2 += (f32x2){t2.y,t2.y}*dtw2[9];
    dtin2 += (f32x2){t2.z,t2.z}*dtw2[10]; dtin2 += (f32x2){t2.w,t2.w}*dtw2[11];
    float dta = (dtin2[0] > 20.f) ? dtin2[0] : __logf(1.f + __expf(dtin2[0]));
    float dtb_ = (dtin2[1] > 20.f) ? dtin2[1] : __logf(1.f + __expf(dtin2[1]));
    cuma += dta; cumb += dtb_;
    if (c != 0)        // chunk 0's dt never read by p2
      *reinterpret_cast<float2*>(dtsav + row*384 + di0) = make_float2(dta, dtb_);
    uint xu = *reinterpret_cast<const uint*>(xcp + row*384);
    uint zu = *reinterpret_cast<const uint*>(zbp2 + row*384);
    float xca = bf2f((ushort)(xu&0xffffu)), xcbv = bf2f((ushort)(xu>>16));
    float zsa = bf2f((ushort)(zu&0xffffu)), zsb = bf2f((ushort)(zu>>16));
    float ua = dta*xca, ub = dtb_*xcbv;
    f32x2 u2a = {ua,ua}, u2b = {ub,ub};
    f32x2 dA2a[8], dA2b[8];
    if (fast){
      build_dA2_fast(__expf(dta*A0a), dA2a);
      build_dA2_fast(__expf(dtb_*A0b), dA2b);
    } else {
      #pragma unroll
      for (int p=0;p<8;p++){
        dA2a[p]=(f32x2){__expf(dta*Abp[2*p]), __expf(dta*Abp[2*p+1])};
        dA2b[p]=(f32x2){__expf(dtb_*Abp[16+2*p]), __expf(dtb_*Abp[16+2*p+1])};
      }
    }
    f32x2 yaa={0.f,0.f}, yba={0.f,0.f}, yab={0.f,0.f}, ybb={0.f,0.f};
    #pragma unroll
    for (int i=0;i<4;i++){
      float4 tb4=pr4[3+i], tc4=pr4[7+i];
      f32x2 B0={tb4.x,tb4.y}, B1={tb4.z,tb4.w};
      f32x2 C0={tc4.x,tc4.y}, C1={tc4.z,tc4.w};
      h2a[2*i]   = dA2a[2*i]*h2a[2*i]     + u2a*B0;
      h2a[2*i+1] = dA2a[2*i+1]*h2a[2*i+1] + u2a*B1;
      yaa += h2a[2*i]*C0;
      yba += h2a[2*i+1]*C1;
      h2b[2*i]   = dA2b[2*i]*h2b[2*i]     + u2b*B0;
      h2b[2*i+1] = dA2b[2*i+1]*h2b[2*i+1] + u2b*B1;
      yab += h2b[2*i]*C0;
      ybb += h2b[2*i+1]*C1;
    }
    Sa += ((yaa[0]+yaa[1])+(yba[0]+yba[1]) + xca*Dv2.x)*zsa;
    Sb += ((yab[0]+yab[1])+(ybb[0]+ybb[1]) + xcbv*Dv2.y)*zsb;
  }
  *reinterpret_cast<float2*>(dtend + ((((size_t)dir*Bc + bl)*NC + c)*384 + di0))
      = make_float2(cuma, cumb);
  size_t hb = ((((size_t)c*2+dir)*Bc + bl)*3 + gg)*2048;
  #pragma unroll
  for (int s=0;s<16;s++)
    *reinterpret_cast<float2*>(hbuf + hb + s*128 + lane*2)
        = make_float2(h2a[s>>1][s&1], h2b[s>>1][s&1]);
  float p0 = Sa*w2c2[0].x + Sb*w2c2[0].y;
  float p1v= Sa*w2c2[1].x + Sb*w2c2[1].y;
  float p2v= Sa*w2c2[2].x + Sb*w2c2[2].y;
  float p3v= Sa*w2c2[3].x + Sb*w2c2[3].y;
  #pragma unroll
  for (int off=32; off>0; off>>=1){
    p0 += __shfl_xor(p0, off); p1v += __shfl_xor(p1v, off);
    p2v += __shfl_xor(p2v, off); p3v += __shfl_xor(p3v, off);
  }
  if (lane==0){
    float* dst = part + ((((size_t)dir*32 + (b0+bl))*3 + gg)*64 + c)*4;
    dst[0]=p0; dst[1]=p1v; dst[2]=p2v; dst[3]=p3v;
  }
}

// ---------------- K4b: combine chunk states (2 channels/thread) ----------------
__global__ __launch_bounds__(256) void k_combine(
    const float* __restrict__ dtend, float* __restrict__ hbuf,
    const float* __restrict__ A0fl, const float* __restrict__ Abuf, int Bc){
  const int gg=blockIdx.x, bl=blockIdx.y, dir=blockIdx.z;      // gg 0..2
  const int wv=threadIdx.x>>6, lane=threadIdx.x&63;
  const int di0=gg*128+lane*2;
  float4 af = *reinterpret_cast<const float4*>(A0fl + ((size_t)dir*384+di0)*2);
  const bool fast = (af.y != 0.f) && (af.w != 0.f);
  const float* Abp = Abuf + ((size_t)dir*384+di0)*16;
  float Aa[4], Ab[4];
  #pragma unroll
  for (int si=0;si<4;si++){
    int s = wv*4+si;
    Aa[si] = fast ? af.x*(float)(s+1) : Abp[s];
    Ab[si] = fast ? af.z*(float)(s+1) : Abp[16+s];
  }
  float2 cur[4];
  size_t hx0 = ((((size_t)(0*2+dir)*Bc+bl)*3+gg)*2048) + (wv*4)*128 + lane*2;
  #pragma unroll
  for (int si=0;si<4;si++) cur[si]=*reinterpret_cast<float2*>(hbuf + hx0 + si*128);
  for (int c=1;c<NC;c++){
    size_t hx=((((size_t)c*2+dir)*Bc+bl)*3+gg)*2048 + (wv*4)*128 + lane*2;
    float2 tmp[4];
    #pragma unroll
    for (int si=0;si<4;si++){
      tmp[si]=*reinterpret_cast<float2*>(hbuf+hx+si*128);
      *reinterpret_cast<float2*>(hbuf+hx+si*128)=cur[si];
    }
    if (c<NC-1){
      float2 Sdt = *reinterpret_cast<const float2*>(dtend + ((((size_t)dir*Bc+bl)*NC + c)*384 + di0));
      #pragma unroll
      for (int si=0;si<4;si++){
        cur[si].x = __expf(Aa[si]*Sdt.x)*cur[si].x + tmp[si].x;
        cur[si].y = __expf(Ab[si]*Sdt.y)*cur[si].y + tmp[si].y;
      }
    }
  }
}

// ---------------- K4c: scan phase 2 (h0 correction), 2 channels/thread, dt from dtsav ----------------
__global__ __launch_bounds__(256) void k_scan_p2(
    const ushort* __restrict__ zb, const float* __restrict__ proj,
    const float* __restrict__ hbuf, const float* __restrict__ dtsav,
    const float* __restrict__ A0fl, const float* __restrict__ Abuf,
    const float* __restrict__ W2, float* __restrict__ part, int b0, int Bc){
  const int dir=blockIdx.z, bl=blockIdx.y;
  const int gg=blockIdx.x>>3, cq=blockIdx.x&7;          // gg 0..2
  const int wv=threadIdx.x>>6, lane=threadIdx.x&63;
  const int c = cq*4 + wv + 1;
  const int di0 = gg*128 + lane*2;
  const size_t seq = ((size_t)dir*Bc + bl)*576;
  if (c >= NC) return;
  float4 af = *reinterpret_cast<const float4*>(A0fl + ((size_t)dir*384+di0)*2);
  const float A0a = af.x, A0b = af.z;
  const bool fast = (af.y != 0.f) && (af.w != 0.f);
  const float* Abp = Abuf + ((size_t)dir*384+di0)*16;
  float2 w2c2[4];
  #pragma unroll
  for (int ch=0;ch<4;ch++)
    w2c2[ch] = *reinterpret_cast<const float2*>(W2 + (ch*2+dir)*384 + di0);
  f32x2 hh2a[8], hh2b[8];
  size_t hb=((((size_t)c*2+dir)*Bc+bl)*3+gg)*2048;
  #pragma unroll
  for (int s=0;s<16;s++){
    float2 v = *reinterpret_cast<const float2*>(hbuf + hb + s*128 + lane*2);
    hh2a[s>>1][s&1]=v.x; hh2b[s>>1][s&1]=v.y;
  }
  float Sa=0.f, Sb=0.f;
  const int l0 = c*CL;
  const int pbase = (int)((seq + (size_t)l0)*44);
  const ushort* zbp2 = zb + di0;
  for (int j=0;j<CL;j++){
    const size_t row = seq + l0 + j;
    const int po = __builtin_amdgcn_readfirstlane(pbase + j*44);
    const float4* pr4 = reinterpret_cast<const float4*>(proj + po);
    float2 dtv = *reinterpret_cast<const float2*>(dtsav + row*384 + di0);
    float dta = dtv.x, dtb_ = dtv.y;
    uint zu = *reinterpret_cast<const uint*>(zbp2 + row*384);
    float zsa = bf2f((ushort)(zu&0xffffu)), zsb = bf2f((ushort)(zu>>16));
    f32x2 dA2a[8], dA2b[8];
    if (fast){
      build_dA2_fast(__expf(dta*A0a), dA2a);
      build_dA2_fast(__expf(dtb_*A0b), dA2b);
    } else {
      #pragma unroll
      for (int p=0;p<8;p++){
        dA2a[p]=(f32x2){__expf(dta*Abp[2*p]), __expf(dta*Abp[2*p+1])};
        dA2b[p]=(f32x2){__expf(dtb_*Abp[16+2*p]), __expf(dtb_*Abp[16+2*p+1])};
      }
    }
    f32x2 yaa={0.f,0.f}, yba={0.f,0.f}, yab={0.f,0.f}, ybb={0.f,0.f};
    #pragma unroll
    for (int i=0;i<4;i++){
      float4 tc4 = pr4[7+i];
      f32x2 C0={tc4.x,tc4.y}, C1={tc4.z,tc4.w};
      hh2a[2*i]   = hh2a[2*i]*dA2a[2*i];
      hh2a[2*i+1] = hh2a[2*i+1]*dA2a[2*i+1];
      yaa += hh2a[2*i]*C0;
      yba += hh2a[2*i+1]*C1;
      hh2b[2*i]   = hh2b[2*i]*dA2b[2*i];
      hh2b[2*i+1] = hh2b[2*i+1]*dA2b[2*i+1];
      yab += hh2b[2*i]*C0;
      ybb += hh2b[2*i+1]*C1;
    }
    Sa += ((yaa[0]+yaa[1])+(yba[0]+yba[1]))*zsa;
    Sb += ((yab[0]+yab[1])+(ybb[0]+ybb[1]))*zsb;
  }
  float p0 = Sa*w2c2[0].x + Sb*w2c2[0].y;
  float p1v= Sa*w2c2[1].x + Sb*w2c2[1].y;
  float p2v= Sa*w2c2[2].x + Sb*w2c2[2].y;
  float p3v= Sa*w2c2[3].x + Sb*w2c2[3].y;
  #pragma unroll
  for (int off=32; off>0; off>>=1){
    p0 += __shfl_xor(p0, off); p1v += __shfl_xor(p1v, off);
    p2v += __shfl_xor(p2v, off); p3v += __shfl_xor(p3v, off);
  }
  if (lane==0){
    float* dst = part + ((((size_t)dir*32 + (b0+bl))*3 + gg)*64 + 32 + c)*4;
    dst[0]=p0; dst[1]=p1v; dst[2]=p2v; dst[3]=p3v;
  }
}

// ---------------- K5: final reduce — 32 blocks x 256 threads (wave = channel) ----------------
__global__ __launch_bounds__(256) void k_final(const float* __restrict__ part,
                                               const float* __restrict__ fc_b,
                                               float* __restrict__ out){
  const int b = blockIdx.x;
  const int ch = threadIdx.x>>6, lane = threadIdx.x&63;
  float s = 0.f;
  for (int i = lane; i < 384; i += 64){
    int c = i & 63;
    if (c == 32) continue;                     // unused slot
    int dg = i >> 6;                           // dir*3 + gg
    int dir = dg >= 3 ? 1 : 0;
    int g = dg - dir*3;
    s += part[((((size_t)dir*32 + b)*3 + g)*64 + c)*4 + ch];
  }
  #pragma unroll
  for (int off=32; off>0; off>>=1) s += __shfl_xor(s, off);
  if (lane==0) out[b*4+ch] = fc_b[ch] + s*(1.0f/576.0f);
}

extern "C" void kernel_launch(void* const* d_in, const int* in_sizes, int n_in,
                              void* d_out, int out_size, void* d_ws, size_t ws_size,
                              hipStream_t stream){
  const float* x       = (const float*)d_in[0];
  const float* patch_w = (const float*)d_in[1];
  const float* patch_b = (const float*)d_in[2];
  const float* ln_g    = (const float*)d_in[3];
  const float* ln_b    = (const float*)d_in[4];
  const float* fc_w    = (const float*)d_in[5];
  const float* fc_b    = (const float*)d_in[6];
  const float* f_in_w  = (const float*)d_in[7];
  const float* f_cw    = (const float*)d_in[8];
  const float* f_cb    = (const float*)d_in[9];
  const float* f_xw    = (const float*)d_in[10];
  const float* f_dtw   = (const float*)d_in[11];
  const float* f_dtb   = (const float*)d_in[12];
  const float* f_al    = (const float*)d_in[13];
  const float* f_D     = (const float*)d_in[14];
  const float* f_ow    = (const float*)d_in[15];
  const float* b_in_w  = (const float*)d_in[16];
  const float* b_cw    = (const float*)d_in[17];
  const float* b_cb    = (const float*)d_in[18];
  const float* b_xw    = (const float*)d_in[19];
  const float* b_dtw   = (const float*)d_in[20];
  const float* b_dtb   = (const float*)d_in[21];
  const float* b_al    = (const float*)d_in[22];
  const float* b_D     = (const float*)d_in[23];
  const float* b_ow    = (const float*)d_in[24];
  float* out = (float*)d_out;
  float* ws  = (float*)d_ws;

  float* W2    = ws;                       // 3072
  float* part  = W2 + 3072;                // 98304 (only 49152 used)
  ushort* pw_h = (ushort*)(part + 98304);  // 147456 ush (plain [n][k])
  ushort* pw_l = pw_h + 147456;
  ushort* iw_h = pw_l + 147456;            // 294912 ush (fragment-packed)
  ushort* iw_l = iw_h + 294912;
  ushort* xw_h = iw_l + 294912;            // 36864 ush
  ushort* xw_l = xw_h + 36864;
  float* cwT   = (float*)(xw_l + 36864);   // 3072
  float* Abuf  = cwT + 3072;               // 12288
  float* A0fl  = Abuf + 12288;             // 1536
  float* base  = A0fl + 1536;

  // floats: perB = tokf 110592 + xib 442368 + zb 221184 + xcb 221184
  //              + dtend 24576 + hbuf 393216 = 1413120 (dtsav aliases xib)
  const size_t FIXED = 597504ull;
  const size_t perB  = 1413120ull;
  int Bc = 32;
  while (Bc > 1 && (FIXED + (size_t)Bc*perB)*4ull > ws_size) Bc >>= 1;

  ushort* tokf_h = (ushort*)base;                   // Bc*110592 ush (fragment-packed)
  ushort* tokf_l = tokf_h + (size_t)Bc*110592ull;
  float* prj  = base;                               // alias (tokf dead by then)
  float* xib  = base + (size_t)Bc*110592ull;
  float* dtsav = xib;                               // alias (xib dead after convx)
  ushort* zbp = (ushort*)(xib + (size_t)Bc*442368ull);
  ushort* xcb = zbp + (size_t)Bc*442368ull;
  float* dtnd = (float*)(xcb + (size_t)Bc*442368ull);
  float* hbf  = dtnd + (size_t)Bc*24576ull;

  k_prep_all<<<dim3(1890),dim3(256),0,stream>>>(patch_w, f_in_w, b_in_w,
                                                f_xw, b_xw, f_cw, b_cw,
                                                f_al, b_al, fc_w, f_ow, b_ow,
                                                pw_h, pw_l, iw_h, iw_l,
                                                xw_h, xw_l, cwT, Abuf, A0fl, W2);

  for (int b0=0; b0<32; b0+=Bc){
    const int Mc = Bc*576;
    k_patch<<<dim3((Mc+63)/64),dim3(1024),0,stream>>>(x, pw_h, pw_l, patch_b,
                                                      ln_g, ln_b, tokf_h, tokf_l, b0, Mc);
    k_inproj<<<dim3((Mc+127)/128,12),dim3(1024),0,stream>>>(tokf_h, tokf_l, iw_h, iw_l,
                                                            xib, zbp, Bc, Mc);
    k_convx<<<dim3(9,Bc,2),dim3(256),0,stream>>>(xib, cwT, f_cb, b_cb,
                                                 xw_h, xw_l, prj, xcb, Bc);
    k_scan_p1<<<dim3(24,Bc,2),dim3(256),0,stream>>>(zbp, xcb, prj,
                                                    f_dtw,b_dtw, f_dtb,b_dtb,
                                                    A0fl, Abuf, f_D,b_D,
                                                    W2, dtnd, hbf, dtsav, part, b0, Bc);
    k_combine<<<dim3(3,Bc,2),dim3(256),0,stream>>>(dtnd, hbf, A0fl, Abuf, Bc);
    k_scan_p2<<<dim3(24,Bc,2),dim3(256),0,stream>>>(zbp, prj, hbf, dtsav,
                                                    A0fl, Abuf, W2, part, b0, Bc);
  }
  k_final<<<dim3(32),dim3(256),0,stream>>>(part, fc_b, out);
}

// Round 11
// 222.312 us; speedup vs baseline: 1.0103x; 1.0103x over previous
//
#include <hip/hip_runtime.h>
#include <hip/hip_bf16.h>

// B=32, L=576, DIM=192, D_INNER=384, D_STATE=16, DT_RANK=12, D_CONV=4
#define NC 32
#define CL 18

typedef __attribute__((ext_vector_type(8))) short short8;
typedef __attribute__((ext_vector_type(4))) float f32x4;
typedef __attribute__((ext_vector_type(2))) float f32x2;

__device__ __forceinline__ float sigm(float x){ return 1.0f/(1.0f+__expf(-x)); }

__device__ __forceinline__ ushort f2bf(float f){
  unsigned u = __float_as_uint(f);
  unsigned r = (u + 0x7fffu + ((u>>16)&1u)) >> 16;
  return (ushort)r;
}
__device__ __forceinline__ float bf2f(ushort h){ return __uint_as_float(((unsigned)h)<<16); }

// log-depth power ladder: dA2[p] = {e1^(2p+1), e1^(2p+2)}  (verified safe in R3/R10)
__device__ __forceinline__ void build_dA2_fast(float e1, f32x2 dA2[8]){
  float e2 = e1*e1;
  f32x2 d0 = {e1, e2};
  float e4 = e2*e2;
  f32x2 e2v = {e2,e2}, e4v = {e4,e4};
  f32x2 d1 = d0*e2v;
  f32x2 d2 = d0*e4v;
  f32x2 d3 = d1*e4v;
  float e8 = e4*e4;
  f32x2 e8v = {e8,e8};
  dA2[0]=d0; dA2[1]=d1; dA2[2]=d2; dA2[3]=d3;
  dA2[4]=d0*e8v; dA2[5]=d1*e8v; dA2[6]=d2*e8v; dA2[7]=d3*e8v;
}

// ---------------- fused preprocessing ----------------
__global__ __launch_bounds__(256) void k_prep_all(
    const float* __restrict__ patch_w, const float* __restrict__ f_in_w,
    const float* __restrict__ b_in_w,
    const float* __restrict__ f_xw, const float* __restrict__ b_xw,
    const float* __restrict__ f_cw, const float* __restrict__ b_cw,
    const float* __restrict__ f_al, const float* __restrict__ b_al,
    const float* __restrict__ fc_w, const float* __restrict__ f_ow,
    const float* __restrict__ b_ow,
    ushort* __restrict__ pw_h, ushort* __restrict__ pw_l,
    ushort* __restrict__ iw_h, ushort* __restrict__ iw_l,
    ushort* __restrict__ xw_h, ushort* __restrict__ xw_l,
    float* __restrict__ cwT, float* __restrict__ Abuf,
    float* __restrict__ A0fl, float* __restrict__ W2){
  const int bx = blockIdx.x, t = threadIdx.x;
  if (bx < 1728){
    int which = bx/576;
    int i = (bx - which*576)*256 + t;          // < 147456
    if (which==0){
      float f = patch_w[i];
      ushort hb = f2bf(f);
      pw_h[i]=hb; pw_l[i]=f2bf(f - bf2f(hb));
    } else {
      const float* src = (which==1) ? f_in_w : b_in_w;
      int dirofs = (which==1) ? 0 : 48;
      float f = src[i];
      int n = i/192, k = i%192;
      int nblk = n>>4, r = n&15, kblk = k>>5, kk = k&31;
      int lane = r + ((kk>>3)<<4), j = kk&7;
      size_t idx = ((size_t)((nblk+dirofs)*6 + kblk)*64 + lane)*8 + j;
      ushort hb = f2bf(f);
      iw_h[idx]=hb; iw_l[idx]=f2bf(f - bf2f(hb));
    }
  } else if (bx < 1872){
    int i = (bx-1728)*256 + t;                 // < 36864
    int dir=i/(48*384), rem=i%(48*384), n=rem/384, k=rem%384;
    float v = (n<44) ? (dir?b_xw:f_xw)[n*384+k] : 0.f;
    ushort hb = f2bf(v);
    xw_h[i]=hb; xw_l[i]=f2bf(v - bf2f(hb));
  } else if (bx < 1884){
    int i = (bx-1872)*256 + t;                 // < 3072
    int dir=i/1536, rem=i%1536, j=rem/384, k=rem%384;
    cwT[i] = (dir ? b_cw : f_cw)[k*4+j];
  } else if (bx < 1887){
    int i = (bx-1884)*256 + t;
    if (i < 768){
      int dir=i/384, di=i%384;
      const float* alp = (dir?b_al:f_al) + di*16;
      float A0 = -expf(alp[0]);
      bool fast = true;
      Abuf[(size_t)i*16] = A0;
      #pragma unroll
      for (int s=1;s<16;s++){
        float A = -expf(alp[s]);
        Abuf[(size_t)i*16+s] = A;
        fast = fast && (fabsf(A - (s+1)*A0) <= 1e-5f*(s+1)*fabsf(A0));
      }
      A0fl[i*2]=A0; A0fl[i*2+1]=fast?1.f:0.f;
    }
  } else {
    int i = (bx-1887)*256 + t;
    if (i < 768){
      int dir=i/384, di=i%384;
      const float* ow = dir ? b_ow : f_ow;
      float a0=0.f,a1=0.f,a2=0.f,a3=0.f;
      for (int d=0; d<192; ++d){
        float o = ow[d*384 + di];
        a0 += fc_w[0*192+d]*o; a1 += fc_w[1*192+d]*o;
        a2 += fc_w[2*192+d]*o; a3 += fc_w[3*192+d]*o;
      }
      W2[(0*2+dir)*384+di]=a0; W2[(1*2+dir)*384+di]=a1;
      W2[(2*2+dir)*384+di]=a2; W2[(3*2+dir)*384+di]=a3;
    }
  }
}

// ---------------- K1: patch embed MFMA GEMM + fused LN -> fragment-packed tokf ----------------
// BM=64, block=1024, 16 waves. Addresses hoisted out of the K-loop (no data prefetch).
__global__ __launch_bounds__(1024) void k_patch(
    const float* __restrict__ x,
    const ushort* __restrict__ pw_h, const ushort* __restrict__ pw_l,
    const float* __restrict__ pb, const float* __restrict__ lng,
    const float* __restrict__ lnb,
    ushort* __restrict__ tokf_h, ushort* __restrict__ tokf_l,
    int b0, int Mc){
  __shared__ __align__(16) char sBmem[49152];   // sBh 24KB + sBl 24KB ; aliased as sT
  __shared__ __align__(16) ushort sAh[64*64], sAl[64*64];  // 8KB + 8KB
  __shared__ float sLN[4][64][2];               // 2KB
  ushort* sBh = (ushort*)sBmem;
  ushort* sBl = (ushort*)(sBmem + 24576);
  const int tid = threadIdx.x;
  const int m0 = blockIdx.x*64;
  const int lane = tid&63, w = tid>>6;          // w 0..15
  const int wr = w>>2, wc = w&3;
  const int r = lane&15, g = lane>>4;
  f32x4 acc[3];
  #pragma unroll
  for (int i=0;i<3;i++) acc[i] = (f32x4){0.f,0.f,0.f,0.f};

  // hoisted per-thread staging geometry
  const int mA = tid>>4, remA = tid&15, ppA = remA>>2, qqA = remA&3;
  const int rmA = m0 + mA;
  const bool okA = (rmA < Mc);
  size_t baseA = 0;
  if (okA){
    int b = b0 + rmA/576, l = rmA%576, hp = l/24, wp = l%24;
    baseA = ((size_t)(b*3)*384 + hp*16 + ppA)*96 + wp*4 + qqA;
  }
  const int byteA = (mA*128 + ppA*32 + qqA*8) ^ ((mA&7)<<4);
  const int nB0 = tid>>3, k8B0 = tid&7;
  const size_t baseB0 = (size_t)nB0*768 + k8B0*8;
  const int byteB0 = (nB0*128 + k8B0*16) ^ ((nB0&7)<<4);
  const bool okB1 = (tid < 512);
  const int fB1 = tid + 1024;
  const int nB1 = fB1>>3, k8B1 = fB1&7;
  const size_t baseB1 = (size_t)nB1*768 + k8B1*8;
  const int byteB1 = (nB1*128 + k8B1*16) ^ ((nB1&7)<<4);

  for (int s=0;s<12;s++){
    {
      float4 v = make_float4(0.f,0.f,0.f,0.f);
      if (okA){
        size_t so = (size_t)((s>>2)*384 + (s&3)*4)*96;   // wave-uniform SALU
        v = reinterpret_cast<const float4*>(x)[baseA + so];
      }
      ushort4 hv, lv;
      hv.x=f2bf(v.x); lv.x=f2bf(v.x-bf2f(hv.x));
      hv.y=f2bf(v.y); lv.y=f2bf(v.y-bf2f(hv.y));
      hv.z=f2bf(v.z); lv.z=f2bf(v.z-bf2f(hv.z));
      hv.w=f2bf(v.w); lv.w=f2bf(v.w-bf2f(hv.w));
      *reinterpret_cast<ushort4*>((char*)sAh + byteA) = hv;
      *reinterpret_cast<ushort4*>((char*)sAl + byteA) = lv;
    }
    {
      uint4 bh = *reinterpret_cast<const uint4*>(pw_h + baseB0 + s*64);
      uint4 bl = *reinterpret_cast<const uint4*>(pw_l + baseB0 + s*64);
      *reinterpret_cast<uint4*>((char*)sBh + byteB0) = bh;
      *reinterpret_cast<uint4*>((char*)sBl + byteB0) = bl;
      if (okB1){
        uint4 bh1 = *reinterpret_cast<const uint4*>(pw_h + baseB1 + s*64);
        uint4 bl1 = *reinterpret_cast<const uint4*>(pw_l + baseB1 + s*64);
        *reinterpret_cast<uint4*>((char*)sBh + byteB1) = bh1;
        *reinterpret_cast<uint4*>((char*)sBl + byteB1) = bl1;
      }
    }
    __syncthreads();
    #pragma unroll
    for (int kk=0;kk<2;kk++){
      int arow = wr*16 + r;
      int abyte = (arow*128 + kk*64 + g*16) ^ ((arow&7)<<4);
      short8 ah = *reinterpret_cast<const short8*>((char*)sAh + abyte);
      short8 al = *reinterpret_cast<const short8*>((char*)sAl + abyte);
      #pragma unroll
      for (int nfl=0; nfl<3; nfl++){
        int brow = (wc*3+nfl)*16 + r;
        int bbyte = (brow*128 + kk*64 + g*16) ^ ((brow&7)<<4);
        short8 bh = *reinterpret_cast<const short8*>((char*)sBh + bbyte);
        short8 bll = *reinterpret_cast<const short8*>((char*)sBl + bbyte);
        acc[nfl] = __builtin_amdgcn_mfma_f32_16x16x32_bf16(ah, bh, acc[nfl], 0,0,0);
        acc[nfl] = __builtin_amdgcn_mfma_f32_16x16x32_bf16(ah, bll, acc[nfl], 0,0,0);
        acc[nfl] = __builtin_amdgcn_mfma_f32_16x16x32_bf16(al, bh, acc[nfl], 0,0,0);
      }
    }
    __syncthreads();
  }
  float pbv[3], gv[3], bv[3];
  #pragma unroll
  for (int nfl=0;nfl<3;nfl++){
    int col = (wc*3+nfl)*16 + r;
    pbv[nfl]=pb[col]; gv[nfl]=lng[col]; bv[nfl]=lnb[col];
  }
  #pragma unroll
  for (int nfl=0;nfl<3;nfl++)
    #pragma unroll
    for (int q=0;q<4;q++) acc[nfl][q] += pbv[nfl];
  float sum[4]={0,0,0,0}, sq[4]={0,0,0,0};
  #pragma unroll
  for (int nfl=0;nfl<3;nfl++)
    #pragma unroll
    for (int q=0;q<4;q++){ float v=acc[nfl][q]; sum[q]+=v; sq[q]+=v*v; }
  #pragma unroll
  for (int off=1; off<16; off<<=1){
    #pragma unroll
    for (int q=0;q<4;q++){
      sum[q]+=__shfl_xor(sum[q],off);
      sq[q] +=__shfl_xor(sq[q],off);
    }
  }
  if (r==0){
    #pragma unroll
    for (int q=0;q<4;q++){
      int row = wr*16 + g*4 + q;
      sLN[wc][row][0]=sum[q]; sLN[wc][row][1]=sq[q];
    }
  }
  __syncthreads();
  float* sT = (float*)sBmem;                    // 64 x 192 f32 (48KB)
  #pragma unroll
  for (int q=0;q<4;q++){
    int rl = wr*16 + g*4 + q;
    float stot = sLN[0][rl][0]+sLN[1][rl][0]+sLN[2][rl][0]+sLN[3][rl][0];
    float qtot = sLN[0][rl][1]+sLN[1][rl][1]+sLN[2][rl][1]+sLN[3][rl][1];
    float mu = stot*(1.f/192.f);
    float var = qtot*(1.f/192.f) - mu*mu;
    float rs = rsqrtf(var + 1e-5f);
    #pragma unroll
    for (int nfl=0;nfl<3;nfl++)
      sT[rl*192 + (wc*3+nfl)*16 + r] = (acc[nfl][q]-mu)*rs*gv[nfl] + bv[nfl];
  }
  __syncthreads();
  const int mB = m0>>4;
  #pragma unroll
  for (int i=0;i<2;i++){
    int fl = tid + 1024*i;                      // < 1536
    if (fl < 1536){
      int mb = fl/384, rem = fl-mb*384, kb = rem>>6, ln = rem&63;
      int rr = ln&15, gq = ln>>4;
      const float* sp = sT + (mb*16+rr)*192 + kb*32 + gq*8;
      short8 hv, lv;
      #pragma unroll
      for (int j=0;j<8;j++){
        float v = sp[j];
        ushort hb = f2bf(v);
        hv[j] = (short)hb;
        lv[j] = (short)f2bf(v - bf2f(hb));
      }
      size_t o = ((size_t)((mB+mb)*6 + kb)*64 + ln)*8;
      *reinterpret_cast<short8*>(tokf_h + o) = hv;
      *reinterpret_cast<short8*>(tokf_l + o) = lv;
    }
  }
}

// ---------------- K2: in_proj MFMA GEMM — LDS-staged 128x128 tiles, vectorized epilogue ----------------
__global__ __launch_bounds__(1024) void k_inproj(
    const ushort* __restrict__ tokf_h, const ushort* __restrict__ tokf_l,
    const ushort* __restrict__ iw_h, const ushort* __restrict__ iw_l,
    float* __restrict__ xib, ushort* __restrict__ zb, int Bc, int Mc){
  __shared__ __align__(16) char sMem[65536];
  ushort* sAh = (ushort*)sMem;                 // 16 frags * 512 ushorts = 16KB
  ushort* sAl = (ushort*)(sMem + 16384);
  ushort* sBh = (ushort*)(sMem + 32768);
  ushort* sBl = (ushort*)(sMem + 49152);
  const int tid = threadIdx.x;
  const int lane = tid&63, w = tid>>6;         // 16 waves
  const int wr = w>>2, wc = w&3;
  const int r = lane&15, g = lane>>4;
  const int m0 = blockIdx.x*128;
  const int mb0 = blockIdx.x*8;
  const int nb0 = blockIdx.y*8;                // iw frag row (dir already encoded: 0..95)
  const int n0d = (blockIdx.y%6)*128;          // col within this dir (0..767)
  const bool dir1 = (blockIdx.y >= 6);
  const bool isZ = ((blockIdx.y%6) >= 3);

  f32x4 acc[2][2];
  #pragma unroll
  for (int a=0;a<2;a++)
    #pragma unroll
    for (int b=0;b<2;b++) acc[a][b] = (f32x4){0.f,0.f,0.f,0.f};

  for (int s=0;s<3;s++){
    {
      const int f = w;
      const int mf = f>>1, kk = f&1;
      const size_t ga = ((size_t)((mb0+mf)*6 + 2*s+kk)*64 + lane)*8;
      const size_t gb = ((size_t)((nb0+mf)*6 + 2*s+kk)*64 + lane)*8;
      const int so = f*512 + lane*8;
      *reinterpret_cast<short8*>(sAh+so) = *reinterpret_cast<const short8*>(tokf_h+ga);
      *reinterpret_cast<short8*>(sBh+so) = *reinterpret_cast<const short8*>(iw_h+gb);
      if (!isZ){
        *reinterpret_cast<short8*>(sAl+so) = *reinterpret_cast<const short8*>(tokf_l+ga);
        *reinterpret_cast<short8*>(sBl+so) = *reinterpret_cast<const short8*>(iw_l+gb);
      }
    }
    __syncthreads();
    #pragma unroll
    for (int kk=0;kk<2;kk++){
      short8 ah[2], al[2];
      #pragma unroll
      for (int mf=0;mf<2;mf++){
        const int fo = ((wr*2+mf)*2+kk)*512 + lane*8;
        ah[mf] = *reinterpret_cast<const short8*>(sAh+fo);
        if (!isZ) al[mf] = *reinterpret_cast<const short8*>(sAl+fo);
      }
      #pragma unroll
      for (int nf=0;nf<2;nf++){
        const int fo = ((wc*2+nf)*2+kk)*512 + lane*8;
        short8 bh = *reinterpret_cast<const short8*>(sBh+fo);
        if (isZ){
          #pragma unroll
          for (int mf=0;mf<2;mf++)
            acc[mf][nf] = __builtin_amdgcn_mfma_f32_16x16x32_bf16(ah[mf], bh, acc[mf][nf], 0,0,0);
        } else {
          short8 bl = *reinterpret_cast<const short8*>(sBl+fo);
          #pragma unroll
          for (int mf=0;mf<2;mf++){
            acc[mf][nf] = __builtin_amdgcn_mfma_f32_16x16x32_bf16(ah[mf], bh, acc[mf][nf], 0,0,0);
            acc[mf][nf] = __builtin_amdgcn_mfma_f32_16x16x32_bf16(ah[mf], bl, acc[mf][nf], 0,0,0);
            acc[mf][nf] = __builtin_amdgcn_mfma_f32_16x16x32_bf16(al[mf], bh, acc[mf][nf], 0,0,0);
          }
        }
      }
    }
    __syncthreads();
  }

  float* sT = reinterpret_cast<float*>(sMem);  // 64 x 132 f32 = 33.8KB
  const int h_of_w = wr>>1;
  #pragma unroll
  for (int h=0; h<2; h++){
    if (h==1) __syncthreads();
    if (h_of_w == h){
      #pragma unroll
      for (int mf=0;mf<2;mf++)
        #pragma unroll
        for (int nf=0;nf<2;nf++)
          #pragma unroll
          for (int q=0;q<4;q++){
            int rl = (wr&1)*32 + mf*16 + g*4 + q;
            int c  = wc*32 + nf*16 + r;
            sT[rl*132 + c] = acc[mf][nf][q];
          }
    }
    __syncthreads();
    {
      const int rl = tid>>4, cg = tid&15;
      const int rm = m0 + h*64 + rl;
      if (rm < Mc){
        size_t row;
        if (dir1){
          int bl = rm/576, l = rm - bl*576;
          row = (size_t)(Bc + bl)*576 + (575-l);
        } else {
          row = (size_t)rm;
        }
        const float* sp = sT + rl*132 + cg*8;
        if (!isZ){
          *reinterpret_cast<f32x4*>(xib + row*384 + n0d + cg*8)     = *reinterpret_cast<const f32x4*>(sp);
          *reinterpret_cast<f32x4*>(xib + row*384 + n0d + cg*8 + 4) = *reinterpret_cast<const f32x4*>(sp+4);
        } else {
          short8 hv;
          #pragma unroll
          for (int j=0;j<8;j++){
            float v = sp[j];
            v = v*sigm(v);
            hv[j] = (short)f2bf(v);
          }
          *reinterpret_cast<short8*>(zb + row*384 + (n0d-384) + cg*8) = hv;
        }
      }
    }
  }
}

// ---------------- K3: fused conv1d+silu+x_proj as MFMA GEMM (N=48), writes xc bf16 ----------------
__global__ __launch_bounds__(256) void k_convx(
    const float* __restrict__ xib, const float* __restrict__ cwT,
    const float* __restrict__ f_cb, const float* __restrict__ b_cb,
    const ushort* __restrict__ xw_h, const ushort* __restrict__ xw_l,
    float* __restrict__ proj, ushort* __restrict__ xcb, int Bc){
  __shared__ __align__(16) float sRaw[67*64];
  __shared__ __align__(16) ushort sAh[64*64], sAl[64*64];
  __shared__ __align__(16) ushort sBh[48*64], sBl[48*64];
  const int dir = blockIdx.z, blk = blockIdx.y, l0 = blockIdx.x*64;
  const int tid = threadIdx.x, lane = tid&63, w = tid>>6;
  const int r = lane&15, g = lane>>4;
  const size_t seq = ((size_t)dir*Bc + blk)*576;
  const float* cwTd = cwT + dir*1536;
  const float* cbp  = dir?b_cb:f_cb;
  const ushort* bhp = xw_h + dir*48*384;
  const ushort* blp = xw_l + dir*48*384;
  f32x4 acc[3];
  #pragma unroll
  for (int i=0;i<3;i++) acc[i] = (f32x4){0.f,0.f,0.f,0.f};

  for (int kc=0; kc<6; ++kc){
    #pragma unroll
    for (int i=0;i<5;i++){
      int f = tid + i*256;
      if (f < 67*16){
        int rr = f>>4, kq = f&15;
        int l = l0 + rr - 3;
        float4 v = make_float4(0.f,0.f,0.f,0.f);
        if (l >= 0) v = *reinterpret_cast<const float4*>(xib + (seq+l)*384 + kc*64 + kq*4);
        int kqs = kq ^ (rr&15);
        *reinterpret_cast<float4*>(sRaw + rr*64 + kqs*4) = v;
      }
    }
    __syncthreads();
    #pragma unroll
    for (int i=0;i<4;i++){
      int f = tid + i*256;                 // < 1024
      int m = f>>4, kq = f&15;
      float4 a = reinterpret_cast<const float4*>(cbp)[kc*16 + kq];
      #pragma unroll
      for (int j=0;j<4;j++){
        int rr = m + j;
        float4 rv = *reinterpret_cast<const float4*>(sRaw + rr*64 + (kq ^ (rr&15))*4);
        float4 cv = reinterpret_cast<const float4*>(cwTd)[j*96 + kc*16 + kq];
        a.x += cv.x*rv.x; a.y += cv.y*rv.y; a.z += cv.z*rv.z; a.w += cv.w*rv.w;
      }
      a.x = a.x*sigm(a.x); a.y = a.y*sigm(a.y); a.z = a.z*sigm(a.z); a.w = a.w*sigm(a.w);
      ushort4 hv, lv;
      hv.x=f2bf(a.x); lv.x=f2bf(a.x-bf2f(hv.x));
      hv.y=f2bf(a.y); lv.y=f2bf(a.y-bf2f(hv.y));
      hv.z=f2bf(a.z); lv.z=f2bf(a.z-bf2f(hv.z));
      hv.w=f2bf(a.w); lv.w=f2bf(a.w-bf2f(hv.w));
      *reinterpret_cast<ushort4*>(xcb + (seq + l0 + m)*384 + kc*64 + kq*4) = hv;
      int byte = (m*128 + kq*8) ^ ((m&7)<<4);
      *reinterpret_cast<ushort4*>((char*)sAh + byte) = hv;
      *reinterpret_cast<ushort4*>((char*)sAl + byte) = lv;
    }
    #pragma unroll
    for (int i=0;i<2;i++){
      int f = tid + i*256;
      if (f < 384){
        int n = f>>3, k8 = f&7;
        size_t gi = (size_t)n*384 + kc*64 + k8*8;
        uint4 vh = *reinterpret_cast<const uint4*>(bhp + gi);
        uint4 vl = *reinterpret_cast<const uint4*>(blp + gi);
        int byte = (n*128 + k8*16) ^ ((n&7)<<4);
        *reinterpret_cast<uint4*>((char*)sBh + byte) = vh;
        *reinterpret_cast<uint4*>((char*)sBl + byte) = vl;
      }
    }
    __syncthreads();
    #pragma unroll
    for (int kk=0;kk<2;kk++){
      int arow = w*16 + r;
      int abyte = (arow*128 + kk*64 + g*16) ^ ((arow&7)<<4);
      short8 ah = *reinterpret_cast<const short8*>((char*)sAh + abyte);
      short8 al = *reinterpret_cast<const short8*>((char*)sAl + abyte);
      #pragma unroll
      for (int nf=0;nf<3;nf++){
        int brow = nf*16 + r;
        int bbyte = (brow*128 + kk*64 + g*16) ^ ((brow&7)<<4);
        short8 bh = *reinterpret_cast<const short8*>((char*)sBh + bbyte);
        short8 bll = *reinterpret_cast<const short8*>((char*)sBl + bbyte);
        acc[nf] = __builtin_amdgcn_mfma_f32_16x16x32_bf16(ah, bh, acc[nf], 0,0,0);
        acc[nf] = __builtin_amdgcn_mfma_f32_16x16x32_bf16(ah, bll, acc[nf], 0,0,0);
        acc[nf] = __builtin_amdgcn_mfma_f32_16x16x32_bf16(al, bh, acc[nf], 0,0,0);
      }
    }
    __syncthreads();
  }
  #pragma unroll
  for (int nf=0;nf<3;nf++){
    int col = nf*16 + r;
    if (col < 44){
      #pragma unroll
      for (int q=0;q<4;q++){
        int l = l0 + w*16 + g*4 + q;
        proj[(seq+l)*44 + col] = acc[nf][q];
      }
    }
  }
}

// ---------------- K4a: chunked scan phase 1 (h0=0), 2 channels/thread; saves dt for p2 ----------------
__global__ __launch_bounds__(256) void k_scan_p1(
    const ushort* __restrict__ zb, const ushort* __restrict__ xcb,
    const float* __restrict__ proj,
    const float* __restrict__ f_dtw, const float* __restrict__ b_dtw,
    const float* __restrict__ f_dtb, const float* __restrict__ b_dtb,
    const float* __restrict__ A0fl, const float* __restrict__ Abuf,
    const float* __restrict__ f_D,  const float* __restrict__ b_D,
    const float* __restrict__ W2, float* __restrict__ dtend,
    float* __restrict__ hbuf, float* __restrict__ dtsav,
    float* __restrict__ part, int b0, int Bc){
  const int dir=blockIdx.z, bl=blockIdx.y;
  const int gg=blockIdx.x>>3, cq=blockIdx.x&7;          // gg 0..2
  const int wv=threadIdx.x>>6, lane=threadIdx.x&63;
  const int c = cq*4 + wv;
  const int di0 = gg*128 + lane*2;
  const size_t seq = ((size_t)dir*Bc + bl)*576;
  const float* dtwp = (dir?b_dtw:f_dtw) + (size_t)di0*12;
  f32x2 dtw2[12];
  {
    const float4* dp = reinterpret_cast<const float4*>(dtwp);
    #pragma unroll
    for (int i=0;i<3;i++){
      float4 fa = dp[i], fb = dp[i+3];
      dtw2[4*i+0] = (f32x2){fa.x, fb.x};
      dtw2[4*i+1] = (f32x2){fa.y, fb.y};
      dtw2[4*i+2] = (f32x2){fa.z, fb.z};
      dtw2[4*i+3] = (f32x2){fa.w, fb.w};
    }
  }
  float2 dtb2 = *reinterpret_cast<const float2*>((dir?b_dtb:f_dtb)+di0);
  float4 af = *reinterpret_cast<const float4*>(A0fl + ((size_t)dir*384+di0)*2);
  const float A0a = af.x, A0b = af.z;
  const bool fast = (af.y != 0.f) && (af.w != 0.f);
  const float* Abp = Abuf + ((size_t)dir*384+di0)*16;   // rows a (0..15), b (16..31)
  float2 Dv2 = *reinterpret_cast<const float2*>((dir?b_D:f_D)+di0);
  float2 w2c2[4];
  #pragma unroll
  for (int ch=0;ch<4;ch++)
    w2c2[ch] = *reinterpret_cast<const float2*>(W2 + (ch*2+dir)*384 + di0);
  f32x2 h2a[8], h2b[8];
  #pragma unroll
  for (int p=0;p<8;p++){ h2a[p]=(f32x2){0.f,0.f}; h2b[p]=(f32x2){0.f,0.f}; }
  float Sa=0.f, Sb=0.f, cuma=0.f, cumb=0.f;
  const int l0 = c*CL;
  const int pbase = (int)((seq + (size_t)l0)*44);
  const ushort* xcp = xcb + di0;
  const ushort* zbp2 = zb + di0;
  for (int j=0;j<CL;j++){
    const size_t row = seq + l0 + j;
    const int po = __builtin_amdgcn_readfirstlane(pbase + j*44);
    const float4* pr4 = reinterpret_cast<const float4*>(proj + po);
    float4 t0=pr4[0], t1=pr4[1], t2=pr4[2];
    f32x2 dtin2 = (f32x2){dtb2.x, dtb2.y};
    dtin2 += (f32x2){t0.x,t0.x}*dtw2[0]; dtin2 += (f32x2){t0.y,t0.y}*dtw2[1];
    dtin2 += (f32x2){t0.z,t0.z}*dtw2[2]; dtin2 += (f32x2){t0.w,t0.w}*dtw2[3];
    dtin2 += (f32x2){t1.x,t1.x}*dtw2[4]; dtin2 += (f32x2){t1.y,t1.y}*dtw2[5];
    dtin2 += (f32x2){t1.z,t1.z}*dtw2[6]; dtin2 += (f32x2){t1.w,t1.w}*dtw2[7];
    dtin2 += (f32x2){t2.x,t2.x}*dtw2[8]; dtin2 += (f32x2){t2.y,t2.y}*dtw2[9];
    dtin2 += (f32x2){t2.z,t2.z}*dtw2[10]; dtin2 += (f32x2){t2.w,t2.w}*dtw2[11];
    float dta = (dtin2[0] > 20.f) ? dtin2[0] : __logf(1.f + __expf(dtin2[0]));
    float dtb_ = (dtin2[1] > 20.f) ? dtin2[1] : __logf(1.f + __expf(dtin2[1]));
    cuma += dta; cumb += dtb_;
    if (c != 0)        // chunk 0's dt never read by p2
      *reinterpret_cast<float2*>(dtsav + row*384 + di0) = make_float2(dta, dtb_);
    uint xu = *reinterpret_cast<const uint*>(xcp + row*384);
    uint zu = *reinterpret_cast<const uint*>(zbp2 + row*384);
    float xca = bf2f((ushort)(xu&0xffffu)), xcbv = bf2f((ushort)(xu>>16));
    float zsa = bf2f((ushort)(zu&0xffffu)), zsb = bf2f((ushort)(zu>>16));
    float ua = dta*xca, ub = dtb_*xcbv;
    f32x2 u2a = {ua,ua}, u2b = {ub,ub};
    f32x2 dA2a[8], dA2b[8];
    if (fast){
      build_dA2_fast(__expf(dta*A0a), dA2a);
      build_dA2_fast(__expf(dtb_*A0b), dA2b);
    } else {
      #pragma unroll
      for (int p=0;p<8;p++){
        dA2a[p]=(f32x2){__expf(dta*Abp[2*p]), __expf(dta*Abp[2*p+1])};
        dA2b[p]=(f32x2){__expf(dtb_*Abp[16+2*p]), __expf(dtb_*Abp[16+2*p+1])};
      }
    }
    f32x2 yaa={0.f,0.f}, yba={0.f,0.f}, yab={0.f,0.f}, ybb={0.f,0.f};
    #pragma unroll
    for (int i=0;i<4;i++){
      float4 tb4=pr4[3+i], tc4=pr4[7+i];
      f32x2 B0={tb4.x,tb4.y}, B1={tb4.z,tb4.w};
      f32x2 C0={tc4.x,tc4.y}, C1={tc4.z,tc4.w};
      h2a[2*i]   = dA2a[2*i]*h2a[2*i]     + u2a*B0;
      h2a[2*i+1] = dA2a[2*i+1]*h2a[2*i+1] + u2a*B1;
      yaa += h2a[2*i]*C0;
      yba += h2a[2*i+1]*C1;
      h2b[2*i]   = dA2b[2*i]*h2b[2*i]     + u2b*B0;
      h2b[2*i+1] = dA2b[2*i+1]*h2b[2*i+1] + u2b*B1;
      yab += h2b[2*i]*C0;
      ybb += h2b[2*i+1]*C1;
    }
    Sa += ((yaa[0]+yaa[1])+(yba[0]+yba[1]) + xca*Dv2.x)*zsa;
    Sb += ((yab[0]+yab[1])+(ybb[0]+ybb[1]) + xcbv*Dv2.y)*zsb;
  }
  *reinterpret_cast<float2*>(dtend + ((((size_t)dir*Bc + bl)*NC + c)*384 + di0))
      = make_float2(cuma, cumb);
  size_t hb = ((((size_t)c*2+dir)*Bc + bl)*3 + gg)*2048;
  #pragma unroll
  for (int s=0;s<16;s++)
    *reinterpret_cast<float2*>(hbuf + hb + s*128 + lane*2)
        = make_float2(h2a[s>>1][s&1], h2b[s>>1][s&1]);
  float p0 = Sa*w2c2[0].x + Sb*w2c2[0].y;
  float p1v= Sa*w2c2[1].x + Sb*w2c2[1].y;
  float p2v= Sa*w2c2[2].x + Sb*w2c2[2].y;
  float p3v= Sa*w2c2[3].x + Sb*w2c2[3].y;
  #pragma unroll
  for (int off=32; off>0; off>>=1){
    p0 += __shfl_xor(p0, off); p1v += __shfl_xor(p1v, off);
    p2v += __shfl_xor(p2v, off); p3v += __shfl_xor(p3v, off);
  }
  if (lane==0){
    float* dst = part + ((((size_t)dir*32 + (b0+bl))*3 + gg)*64 + c)*4;
    dst[0]=p0; dst[1]=p1v; dst[2]=p2v; dst[3]=p3v;
  }
}

// ---------------- K4b: combine chunk states (2 channels/thread) ----------------
__global__ __launch_bounds__(256) void k_combine(
    const float* __restrict__ dtend, float* __restrict__ hbuf,
    const float* __restrict__ A0fl, const float* __restrict__ Abuf, int Bc){
  const int gg=blockIdx.x, bl=blockIdx.y, dir=blockIdx.z;      // gg 0..2
  const int wv=threadIdx.x>>6, lane=threadIdx.x&63;
  const int di0=gg*128+lane*2;
  float4 af = *reinterpret_cast<const float4*>(A0fl + ((size_t)dir*384+di0)*2);
  const bool fast = (af.y != 0.f) && (af.w != 0.f);
  const float* Abp = Abuf + ((size_t)dir*384+di0)*16;
  float Aa[4], Ab[4];
  #pragma unroll
  for (int si=0;si<4;si++){
    int s = wv*4+si;
    Aa[si] = fast ? af.x*(float)(s+1) : Abp[s];
    Ab[si] = fast ? af.z*(float)(s+1) : Abp[16+s];
  }
  float2 cur[4];
  size_t hx0 = ((((size_t)(0*2+dir)*Bc+bl)*3+gg)*2048) + (wv*4)*128 + lane*2;
  #pragma unroll
  for (int si=0;si<4;si++) cur[si]=*reinterpret_cast<float2*>(hbuf + hx0 + si*128);
  for (int c=1;c<NC;c++){
    size_t hx=((((size_t)c*2+dir)*Bc+bl)*3+gg)*2048 + (wv*4)*128 + lane*2;
    float2 tmp[4];
    #pragma unroll
    for (int si=0;si<4;si++){
      tmp[si]=*reinterpret_cast<float2*>(hbuf+hx+si*128);
      *reinterpret_cast<float2*>(hbuf+hx+si*128)=cur[si];
    }
    if (c<NC-1){
      float2 Sdt = *reinterpret_cast<const float2*>(dtend + ((((size_t)dir*Bc+bl)*NC + c)*384 + di0));
      #pragma unroll
      for (int si=0;si<4;si++){
        cur[si].x = __expf(Aa[si]*Sdt.x)*cur[si].x + tmp[si].x;
        cur[si].y = __expf(Ab[si]*Sdt.y)*cur[si].y + tmp[si].y;
      }
    }
  }
}

// ---------------- K4c: scan phase 2 (h0 correction), 2 channels/thread, dt from dtsav ----------------
// j-loop unrolled x2: hh chain is serial across steps; unrolling lets the scheduler
// overlap step j+1's independent loads/exp/ladder with step j's chain.
__global__ __launch_bounds__(256) void k_scan_p2(
    const ushort* __restrict__ zb, const float* __restrict__ proj,
    const float* __restrict__ hbuf, const float* __restrict__ dtsav,
    const float* __restrict__ A0fl, const float* __restrict__ Abuf,
    const float* __restrict__ W2, float* __restrict__ part, int b0, int Bc){
  const int dir=blockIdx.z, bl=blockIdx.y;
  const int gg=blockIdx.x>>3, cq=blockIdx.x&7;          // gg 0..2
  const int wv=threadIdx.x>>6, lane=threadIdx.x&63;
  const int c = cq*4 + wv + 1;
  const int di0 = gg*128 + lane*2;
  const size_t seq = ((size_t)dir*Bc + bl)*576;
  if (c >= NC) return;
  float4 af = *reinterpret_cast<const float4*>(A0fl + ((size_t)dir*384+di0)*2);
  const float A0a = af.x, A0b = af.z;
  const bool fast = (af.y != 0.f) && (af.w != 0.f);
  const float* Abp = Abuf + ((size_t)dir*384+di0)*16;
  float2 w2c2[4];
  #pragma unroll
  for (int ch=0;ch<4;ch++)
    w2c2[ch] = *reinterpret_cast<const float2*>(W2 + (ch*2+dir)*384 + di0);
  f32x2 hh2a[8], hh2b[8];
  size_t hb=((((size_t)c*2+dir)*Bc+bl)*3+gg)*2048;
  #pragma unroll
  for (int s=0;s<16;s++){
    float2 v = *reinterpret_cast<const float2*>(hbuf + hb + s*128 + lane*2);
    hh2a[s>>1][s&1]=v.x; hh2b[s>>1][s&1]=v.y;
  }
  float Sa=0.f, Sb=0.f;
  const int l0 = c*CL;
  const int pbase = (int)((seq + (size_t)l0)*44);
  const ushort* zbp2 = zb + di0;
  #pragma unroll 2
  for (int j=0;j<CL;j++){
    const size_t row = seq + l0 + j;
    const int po = __builtin_amdgcn_readfirstlane(pbase + j*44);
    const float4* pr4 = reinterpret_cast<const float4*>(proj + po);
    float2 dtv = *reinterpret_cast<const float2*>(dtsav + row*384 + di0);
    float dta = dtv.x, dtb_ = dtv.y;
    uint zu = *reinterpret_cast<const uint*>(zbp2 + row*384);
    float zsa = bf2f((ushort)(zu&0xffffu)), zsb = bf2f((ushort)(zu>>16));
    f32x2 dA2a[8], dA2b[8];
    if (fast){
      build_dA2_fast(__expf(dta*A0a), dA2a);
      build_dA2_fast(__expf(dtb_*A0b), dA2b);
    } else {
      #pragma unroll
      for (int p=0;p<8;p++){
        dA2a[p]=(f32x2){__expf(dta*Abp[2*p]), __expf(dta*Abp[2*p+1])};
        dA2b[p]=(f32x2){__expf(dtb_*Abp[16+2*p]), __expf(dtb_*Abp[16+2*p+1])};
      }
    }
    f32x2 yaa={0.f,0.f}, yba={0.f,0.f}, yab={0.f,0.f}, ybb={0.f,0.f};
    #pragma unroll
    for (int i=0;i<4;i++){
      float4 tc4 = pr4[7+i];
      f32x2 C0={tc4.x,tc4.y}, C1={tc4.z,tc4.w};
      hh2a[2*i]   = hh2a[2*i]*dA2a[2*i];
      hh2a[2*i+1] = hh2a[2*i+1]*dA2a[2*i+1];
      yaa += hh2a[2*i]*C0;
      yba += hh2a[2*i+1]*C1;
      hh2b[2*i]   = hh2b[2*i]*dA2b[2*i];
      hh2b[2*i+1] = hh2b[2*i+1]*dA2b[2*i+1];
      yab += hh2b[2*i]*C0;
      ybb += hh2b[2*i+1]*C1;
    }
    Sa += ((yaa[0]+yaa[1])+(yba[0]+yba[1]))*zsa;
    Sb += ((yab[0]+yab[1])+(ybb[0]+ybb[1]))*zsb;
  }
  float p0 = Sa*w2c2[0].x + Sb*w2c2[0].y;
  float p1v= Sa*w2c2[1].x + Sb*w2c2[1].y;
  float p2v= Sa*w2c2[2].x + Sb*w2c2[2].y;
  float p3v= Sa*w2c2[3].x + Sb*w2c2[3].y;
  #pragma unroll
  for (int off=32; off>0; off>>=1){
    p0 += __shfl_xor(p0, off); p1v += __shfl_xor(p1v, off);
    p2v += __shfl_xor(p2v, off); p3v += __shfl_xor(p3v, off);
  }
  if (lane==0){
    float* dst = part + ((((size_t)dir*32 + (b0+bl))*3 + gg)*64 + 32 + c)*4;
    dst[0]=p0; dst[1]=p1v; dst[2]=p2v; dst[3]=p3v;
  }
}

// ---------------- K5: final reduce — 32 blocks x 256 threads (wave = channel) ----------------
__global__ __launch_bounds__(256) void k_final(const float* __restrict__ part,
                                               const float* __restrict__ fc_b,
                                               float* __restrict__ out){
  const int b = blockIdx.x;
  const int ch = threadIdx.x>>6, lane = threadIdx.x&63;
  float s = 0.f;
  for (int i = lane; i < 384; i += 64){
    int c = i & 63;
    if (c == 32) continue;                     // unused slot
    int dg = i >> 6;                           // dir*3 + gg
    int dir = dg >= 3 ? 1 : 0;
    int g = dg - dir*3;
    s += part[((((size_t)dir*32 + b)*3 + g)*64 + c)*4 + ch];
  }
  #pragma unroll
  for (int off=32; off>0; off>>=1) s += __shfl_xor(s, off);
  if (lane==0) out[b*4+ch] = fc_b[ch] + s*(1.0f/576.0f);
}

extern "C" void kernel_launch(void* const* d_in, const int* in_sizes, int n_in,
                              void* d_out, int out_size, void* d_ws, size_t ws_size,
                              hipStream_t stream){
  const float* x       = (const float*)d_in[0];
  const float* patch_w = (const float*)d_in[1];
  const float* patch_b = (const float*)d_in[2];
  const float* ln_g    = (const float*)d_in[3];
  const float* ln_b    = (const float*)d_in[4];
  const float* fc_w    = (const float*)d_in[5];
  const float* fc_b    = (const float*)d_in[6];
  const float* f_in_w  = (const float*)d_in[7];
  const float* f_cw    = (const float*)d_in[8];
  const float* f_cb    = (const float*)d_in[9];
  const float* f_xw    = (const float*)d_in[10];
  const float* f_dtw   = (const float*)d_in[11];
  const float* f_dtb   = (const float*)d_in[12];
  const float* f_al    = (const float*)d_in[13];
  const float* f_D     = (const float*)d_in[14];
  const float* f_ow    = (const float*)d_in[15];
  const float* b_in_w  = (const float*)d_in[16];
  const float* b_cw    = (const float*)d_in[17];
  const float* b_cb    = (const float*)d_in[18];
  const float* b_xw    = (const float*)d_in[19];
  const float* b_dtw   = (const float*)d_in[20];
  const float* b_dtb   = (const float*)d_in[21];
  const float* b_al    = (const float*)d_in[22];
  const float* b_D     = (const float*)d_in[23];
  const float* b_ow    = (const float*)d_in[24];
  float* out = (float*)d_out;
  float* ws  = (float*)d_ws;

  float* W2    = ws;                       // 3072
  float* part  = W2 + 3072;                // 98304 (only 49152 used)
  ushort* pw_h = (ushort*)(part + 98304);  // 147456 ush (plain [n][k])
  ushort* pw_l = pw_h + 147456;
  ushort* iw_h = pw_l + 147456;            // 294912 ush (fragment-packed)
  ushort* iw_l = iw_h + 294912;
  ushort* xw_h = iw_l + 294912;            // 36864 ush
  ushort* xw_l = xw_h + 36864;
  float* cwT   = (float*)(xw_l + 36864);   // 3072
  float* Abuf  = cwT + 3072;               // 12288
  float* A0fl  = Abuf + 12288;             // 1536
  float* base  = A0fl + 1536;

  // floats: perB = tokf 110592 + xib 442368 + zb 221184 + xcb 221184
  //              + dtend 24576 + hbuf 393216 = 1413120 (dtsav aliases xib)
  const size_t FIXED = 597504ull;
  const size_t perB  = 1413120ull;
  int Bc = 32;
  while (Bc > 1 && (FIXED + (size_t)Bc*perB)*4ull > ws_size) Bc >>= 1;

  ushort* tokf_h = (ushort*)base;                   // Bc*110592 ush (fragment-packed)
  ushort* tokf_l = tokf_h + (size_t)Bc*110592ull;
  float* prj  = base;                               // alias (tokf dead by then)
  float* xib  = base + (size_t)Bc*110592ull;
  float* dtsav = xib;                               // alias (xib dead after convx)
  ushort* zbp = (ushort*)(xib + (size_t)Bc*442368ull);
  ushort* xcb = zbp + (size_t)Bc*442368ull;
  float* dtnd = (float*)(xcb + (size_t)Bc*442368ull);
  float* hbf  = dtnd + (size_t)Bc*24576ull;

  k_prep_all<<<dim3(1890),dim3(256),0,stream>>>(patch_w, f_in_w, b_in_w,
                                                f_xw, b_xw, f_cw, b_cw,
                                                f_al, b_al, fc_w, f_ow, b_ow,
                                                pw_h, pw_l, iw_h, iw_l,
                                                xw_h, xw_l, cwT, Abuf, A0fl, W2);

  for (int b0=0; b0<32; b0+=Bc){
    const int Mc = Bc*576;
    k_patch<<<dim3((Mc+63)/64),dim3(1024),0,stream>>>(x, pw_h, pw_l, patch_b,
                                                      ln_g, ln_b, tokf_h, tokf_l, b0, Mc);
    k_inproj<<<dim3((Mc+127)/128,12),dim3(1024),0,stream>>>(tokf_h, tokf_l, iw_h, iw_l,
                                                            xib, zbp, Bc, Mc);
    k_convx<<<dim3(9,Bc,2),dim3(256),0,stream>>>(xib, cwT, f_cb, b_cb,
                                                 xw_h, xw_l, prj, xcb, Bc);
    k_scan_p1<<<dim3(24,Bc,2),dim3(256),0,stream>>>(zbp, xcb, prj,
                                                    f_dtw,b_dtw, f_dtb,b_dtb,
                                                    A0fl, Abuf, f_D,b_D,
                                                    W2, dtnd, hbf, dtsav, part, b0, Bc);
    k_combine<<<dim3(3,Bc,2),dim3(256),0,stream>>>(dtnd, hbf, A0fl, Abuf, Bc);
    k_scan_p2<<<dim3(24,Bc,2),dim3(256),0,stream>>>(zbp, prj, hbf, dtsav,
                                                    A0fl, Abuf, W2, part, b0, Bc);
  }
  k_final<<<dim3(32),dim3(256),0,stream>>>(part, fc_b, out);
}